// Round 7
// baseline (671.740 us; speedup 1.0000x reference)
//
#include <hip/hip_runtime.h>

typedef unsigned short u16;
typedef __attribute__((ext_vector_type(8))) short short8;
typedef __attribute__((ext_vector_type(4))) float float4v;

#define BTH (512*256*128)   // elements per output tensor
#define MASKV (-30000.0f)

__device__ __forceinline__ u16 f2bf(float f){
    union{float f; unsigned i;} v; v.f = f;
    unsigned x = v.i;
    unsigned r = (x + 0x7FFFu + ((x >> 16) & 1u)) >> 16;  // RNE
    return (u16)r;
}

// ---------------- Kernel 0: f32 weights -> bf16 WT[3][128 n][128 k]; fold C^-0.5 into Wq.
__global__ void wt_kernel(const float* __restrict__ Wq, const float* __restrict__ Wk,
                          const float* __restrict__ Wv, u16* __restrict__ WT){
    int idx = blockIdx.x * 256 + threadIdx.x;   // 0..49151
    int w   = idx >> 14;
    int rem = idx & 16383;
    int n = rem >> 7;
    int k = rem & 127;
    const float* src = (w == 0) ? Wq : (w == 1) ? Wk : Wv;
    float val = src[k * 128 + n];
    if (w == 0) val *= 0.08838834764831845f;    // 128^-0.5
    WT[idx] = f2bf(val);
}

// ============================================================================
// fused_kernel: one block = HALF a batch (128 q-rows); 1024 blocks x 512 thr
// (8 waves).  LDS = 80 KB exactly -> 2 blocks/CU: two INDEPENDENT blocks
// interleave their phases on a CU (one drains proj stores while the other
// runs attn MFMAs) -- r6 showed lockstep waves in ONE block don't overlap.
//
// Causality across the half boundary: two-pass online softmax.
//   hi=0 block: 1 pass  (own keys 0..127, causal mask).
//   hi=1 block: pass 0 = RECOMPUTE low half's K/V proj into LDS (no stores),
//               attend keys 0..127 unmasked; pass 1 = own proj (with stores),
//               attend keys 128..255 with diagonal mask.
//
// LDS (80 KiB):
//   Kbuf  [4 ks][128 key][32]  bf16 (32 KB)  -- pre-K: per-wave 4 KB Q scratch
//   VTbuf [4 ck][128 h][32]    bf16 (32 KB)
//   ps    [8 wave][16][64]     bf16 (16 KB)  P transpose (unpadded)
//
// Wave w owns local row-tile TILE8[w] (permutation balances causal triangle
// across SIMD pairs {w, w+4}: sums {8,10,10,8}).
// ============================================================================
__global__ __launch_bounds__(512, 4) void fused_kernel(const float* __restrict__ x,
                                                       const u16* __restrict__ WT,
                                                       float* __restrict__ dout){
    __shared__ u16 Kbuf [4 * 128 * 32];   // 32 KB
    __shared__ u16 VTbuf[4 * 128 * 32];   // 32 KB
    __shared__ u16 ps   [8 * 1024];       // 16 KB

    int lb = blockIdx.x;
    int b = lb >> 1, hi = lb & 1;
    int r0 = hi << 7;                     // local row base of this half
    int tid = threadIdx.x;
    int w = tid >> 6, lane = tid & 63, lq = lane & 15, quad = lane >> 4;

    const int TILE8[8] = {0,7,3,4, 6,1,5,2};
    int lt = TILE8[w];                    // local 16-row tile within the half

    const float* xb   = x    + (size_t)b * 256 * 128;
    float*       oout = dout + (size_t)b * 256 * 128;
    float*       kout = dout + (size_t)BTH     + (size_t)b * 256 * 128;
    float*       vout = dout + (size_t)2 * BTH + (size_t)b * 256 * 128;

    // ---- Q projection for own rows -> per-wave scratch (Kbuf slice) -> A-frags
    short8 qf[4];
    {
        short8 axq[4];
        #pragma unroll
        for (int ks = 0; ks < 4; ks++){
            const float* px = xb + (size_t)(r0 + lt*16 + lq)*128 + ks*32 + quad*8;
            float4v lo = *(const float4v*)px;
            float4v hiv = *(const float4v*)(px + 4);
            short8 s;
            #pragma unroll
            for (int j = 0; j < 4; j++){ s[j] = (short)f2bf(lo[j]); s[j+4] = (short)f2bf(hiv[j]); }
            axq[ks] = s;
        }
        u16* qs = Kbuf + w * 2048;        // [16][128] u16 = 4096 B
        #pragma unroll
        for (int ht = 0; ht < 8; ht++){
            short8 bw[4];
            #pragma unroll
            for (int ks = 0; ks < 4; ks++)
                bw[ks] = *(const short8*)(WT + (size_t)(ht*16 + lq)*128 + ks*32 + quad*8);
            float4v c = {0.f,0.f,0.f,0.f};
            #pragma unroll
            for (int ks = 0; ks < 4; ks++)
                c = __builtin_amdgcn_mfma_f32_16x16x32_bf16(axq[ks], bw[ks], c, 0, 0, 0);
            #pragma unroll
            for (int r = 0; r < 4; r++)
                qs[(quad*4 + r)*128 + ht*16 + lq] = f2bf(c[r]);   // D: row=q-row, col=h
        }
        #pragma unroll
        for (int ks = 0; ks < 4; ks++)
            qf[ks] = *(const short8*)(qs + lq*128 + ks*32 + quad*8);  // A: row=lq
    }
    __syncthreads();   // Q scratch dead; Kbuf may hold K

    // ---- online-softmax state (persists across passes)
    float4v oacc[8];
    float mrun[4], lrun[4];
    #pragma unroll
    for (int o = 0; o < 8; o++) oacc[o] = (float4v){0.f,0.f,0.f,0.f};
    #pragma unroll
    for (int r = 0; r < 4; r++){ mrun[r] = MASKV; lrun[r] = 0.f; }
    u16* psw = ps + w * 1024;             // [16 rows][64 keys] bf16

    for (int p = 0; p <= hi; p++){
        bool own = (p == hi);             // wave-uniform (hi uniform per block)
        int srcr0 = own ? r0 : 0;         // key-row base of this pass

        // x fragments for the pass's 16 source rows
        short8 axp[4];
        #pragma unroll
        for (int ks = 0; ks < 4; ks++){
            const float* px = xb + (size_t)(srcr0 + lt*16 + lq)*128 + ks*32 + quad*8;
            float4v lo = *(const float4v*)px;
            float4v hiv = *(const float4v*)(px + 4);
            short8 s;
            #pragma unroll
            for (int j = 0; j < 4; j++){ s[j] = (short)f2bf(lo[j]); s[j+4] = (short)f2bf(hiv[j]); }
            axp[ks] = s;
        }

        // K projection -> Kbuf (+ f32 store iff own)
        #pragma unroll
        for (int ht = 0; ht < 8; ht++){
            short8 bw[4];
            #pragma unroll
            for (int ks = 0; ks < 4; ks++)
                bw[ks] = *(const short8*)(WT + (size_t)16384 + (size_t)(ht*16 + lq)*128 + ks*32 + quad*8);
            float4v c = {0.f,0.f,0.f,0.f};
            #pragma unroll
            for (int ks = 0; ks < 4; ks++)
                c = __builtin_amdgcn_mfma_f32_16x16x32_bf16(axp[ks], bw[ks], c, 0, 0, 0);
            #pragma unroll
            for (int r = 0; r < 4; r++){
                int keyl = lt*16 + quad*4 + r;
                if (own) kout[(size_t)(srcr0 + keyl)*128 + ht*16 + lq] = c[r];
                Kbuf[(ht>>1)*4096 + keyl*32 + (ht&1)*16 + lq] = f2bf(c[r]);
            }
        }
        // V projection (f32 store iff own) + V^T (swapped MFMA) -> VTbuf
        #pragma unroll
        for (int ht = 0; ht < 8; ht++){
            short8 bv[4];
            #pragma unroll
            for (int ks = 0; ks < 4; ks++)
                bv[ks] = *(const short8*)(WT + (size_t)2*16384 + (size_t)(ht*16 + lq)*128 + ks*32 + quad*8);
            if (own){
                float4v c = {0.f,0.f,0.f,0.f};
                #pragma unroll
                for (int ks = 0; ks < 4; ks++)
                    c = __builtin_amdgcn_mfma_f32_16x16x32_bf16(axp[ks], bv[ks], c, 0, 0, 0);
                #pragma unroll
                for (int r = 0; r < 4; r++)
                    vout[(size_t)(srcr0 + lt*16 + quad*4 + r)*128 + ht*16 + lq] = c[r];
            }
            float4v ct = {0.f,0.f,0.f,0.f};
            #pragma unroll
            for (int ks = 0; ks < 4; ks++)
                ct = __builtin_amdgcn_mfma_f32_16x16x32_bf16(bv[ks], axp[ks], ct, 0, 0, 0);
            int tl = lt*16 + lq;
            #pragma unroll
            for (int r = 0; r < 4; r++)
                VTbuf[(tl>>5)*4096 + (ht*16 + quad*4 + r)*32 + (tl&31)] = f2bf(ct[r]);
        }
        __syncthreads();   // K / V^T images for this pass complete

        // ---- attention over this pass's 2 key-chunks of 64
        #pragma unroll
        for (int kbL = 0; kbL < 2; kbL++){
            if (own && kbL*4 > lt) continue;   // chunk above diagonal (wave-uniform)

            float4v s4[4];
            #pragma unroll
            for (int kt2 = 0; kt2 < 4; kt2++){
                int kt = kbL*4 + kt2;          // local key tile 0..7
                float4v c = {MASKV, MASKV, MASKV, MASKV};
                if (!own || kt <= lt){
                    c = (float4v){0.f,0.f,0.f,0.f};
                    #pragma unroll
                    for (int ks = 0; ks < 4; ks++){
                        short8 bb = *(const short8*)(Kbuf + ks*4096 + (kt*16 + lq)*32 + quad*8);
                        c = __builtin_amdgcn_mfma_f32_16x16x32_bf16(qf[ks], bb, c, 0, 0, 0);
                    }
                    #pragma unroll
                    for (int r = 0; r < 4; r++)
                        c[r] = fminf(fmaxf(c[r], MASKV), 30000.0f);   // NaN/inf scrub
                    if (own && kt == lt){       // diagonal tile
                        #pragma unroll
                        for (int r = 0; r < 4; r++)
                            if (lq > quad*4 + r) c[r] = MASKV;
                    }
                }
                s4[kt2] = c;
            }
            // online softmax update (quad's 16 lanes hold one row's 64 cols)
            #pragma unroll
            for (int r = 0; r < 4; r++){
                float mx = fmaxf(fmaxf(s4[0][r], s4[1][r]), fmaxf(s4[2][r], s4[3][r]));
                mx = fmaxf(mx, __shfl_xor(mx, 1));
                mx = fmaxf(mx, __shfl_xor(mx, 2));
                mx = fmaxf(mx, __shfl_xor(mx, 4));
                mx = fmaxf(mx, __shfl_xor(mx, 8));
                float mnew = fmaxf(mrun[r], mx);
                float alpha = __expf(mrun[r] - mnew);
                float rs = 0.f;
                #pragma unroll
                for (int kt2 = 0; kt2 < 4; kt2++){
                    float pv = __expf(s4[kt2][r] - mnew);
                    s4[kt2][r] = pv;
                    rs += pv;
                }
                rs += __shfl_xor(rs, 1);
                rs += __shfl_xor(rs, 2);
                rs += __shfl_xor(rs, 4);
                rs += __shfl_xor(rs, 8);
                lrun[r] = lrun[r] * alpha + rs;
                mrun[r] = mnew;
                #pragma unroll
                for (int o = 0; o < 8; o++) oacc[o][r] *= alpha;
            }
            // P: C/D-layout -> per-wave LDS -> A-layout (same-wave ordering)
            #pragma unroll
            for (int kt2 = 0; kt2 < 4; kt2++)
                #pragma unroll
                for (int r = 0; r < 4; r++)
                    psw[(quad*4 + r)*64 + kt2*16 + lq] = f2bf(s4[kt2][r]);
            short8 pa0 = *(const short8*)(psw + lq*64 + quad*8);
            short8 pa1 = *(const short8*)(psw + lq*64 + 32 + quad*8);
            // O += P V
            #pragma unroll
            for (int k2 = 0; k2 < 2; k2++){
                short8 pa = (k2 == 0) ? pa0 : pa1;
                #pragma unroll
                for (int o = 0; o < 8; o++){
                    short8 vb = *(const short8*)(VTbuf + (kbL*2 + k2)*4096 + (o*16 + lq)*32 + quad*8);
                    oacc[o] = __builtin_amdgcn_mfma_f32_16x16x32_bf16(pa, vb, oacc[o], 0, 0, 0);
                }
            }
        }
        if (p < hi) __syncthreads();   // all waves done with Kbuf/VTbuf before next pass
    }

    // ---- epilogue: out = oacc / lrun
    #pragma unroll
    for (int r = 0; r < 4; r++){
        float inv = 1.0f / lrun[r];
        int row = r0 + lt*16 + quad*4 + r;
        #pragma unroll
        for (int o = 0; o < 8; o++)
            oout[(size_t)row*128 + o*16 + lq] = oacc[o][r] * inv;
    }
}

extern "C" void kernel_launch(void* const* d_in, const int* in_sizes, int n_in,
                              void* d_out, int out_size, void* d_ws, size_t ws_size,
                              hipStream_t stream){
    const float* x  = (const float*)d_in[0];
    const float* Wk = (const float*)d_in[1];
    const float* Wq = (const float*)d_in[2];
    const float* Wv = (const float*)d_in[3];
    float* out = (float*)d_out;
    u16* WT = (u16*)d_ws;                         // 96 KB (always available)

    wt_kernel   <<<192,  256, 0, stream>>>(Wq, Wk, Wv, WT);
    fused_kernel<<<1024, 512, 0, stream>>>(x, WT, out);
}

// Round 8
// 469.789 us; speedup vs baseline: 1.4299x; 1.4299x over previous
//
#include <hip/hip_runtime.h>

typedef unsigned short u16;
typedef __attribute__((ext_vector_type(8))) short short8;
typedef __attribute__((ext_vector_type(4))) float float4v;

#define BTH (512*256*128)   // elements per output tensor
#define MASKV (-30000.0f)

__device__ __forceinline__ u16 f2bf(float f){
    union{float f; unsigned i;} v; v.f = f;
    unsigned x = v.i;
    unsigned r = (x + 0x7FFFu + ((x >> 16) & 1u)) >> 16;  // RNE
    return (u16)r;
}

// LDS-only barrier: drain ds ops, NOT global stores (they have no in-kernel
// readers).  Lets k/v/out store traffic overlap the next compute phase.
// sched_barrier(0) pins the waitcnt (guide rule #18).
__device__ __forceinline__ void bar_lds(){
    asm volatile("s_waitcnt lgkmcnt(0)" ::: "memory");
    __builtin_amdgcn_sched_barrier(0);
    __builtin_amdgcn_s_barrier();
}

// ---------------- Kernel 0: f32 weights -> bf16 WT[3][128 n][128 k]; fold C^-0.5 into Wq.
__global__ void wt_kernel(const float* __restrict__ Wq, const float* __restrict__ Wk,
                          const float* __restrict__ Wv, u16* __restrict__ WT){
    int idx = blockIdx.x * 256 + threadIdx.x;   // 0..49151
    int w   = idx >> 14;
    int rem = idx & 16383;
    int n = rem >> 7;
    int k = rem & 127;
    const float* src = (w == 0) ? Wq : (w == 1) ? Wk : Wv;
    float val = src[k * 128 + n];
    if (w == 0) val *= 0.08838834764831845f;    // 128^-0.5
    WT[idx] = f2bf(val);
}

// ============================================================================
// fused_kernel: one block = HALF a batch (128 q-rows); 1024 blocks x 512 thr.
// LDS 80 KB -> 2 blocks/CU.  r7's runtime pass-loop spilled (~1.1 GB scratch
// traffic); here the pass structure is fully specialized at compile time
// (template<bool>, force-inlined) -> straight-line code like r6 (no spill).
//
//   hi=0 block: proj(own,stores) ; attn(causal)
//   hi=1 block: proj(low,NO stores) ; attn(unmasked) ;
//               proj(own,stores)    ; attn(causal)      [online softmax]
//
// LDS: Kbuf [4ks][128key][32] 32KB (pre-K: per-wave 4KB Q scratch)
//      VTbuf[4ck][128h][32]  32KB ; ps [8][16][64] 16KB
// ============================================================================

template<bool OWN>
__device__ __forceinline__ void proj_pass(const float* __restrict__ xb,
                                          const u16* __restrict__ WT,
                                          float* __restrict__ kout,
                                          float* __restrict__ vout,
                                          u16* Kbuf, u16* VTbuf,
                                          int srcr0, int lt, int lq, int quad){
    // x fragments for the pass's 16 source rows (f32 -> bf16)
    short8 axp[4];
    #pragma unroll
    for (int ks = 0; ks < 4; ks++){
        const float* px = xb + (size_t)(srcr0 + lt*16 + lq)*128 + ks*32 + quad*8;
        float4v lo = *(const float4v*)px;
        float4v hv = *(const float4v*)(px + 4);
        short8 s;
        #pragma unroll
        for (int j = 0; j < 4; j++){ s[j] = (short)f2bf(lo[j]); s[j+4] = (short)f2bf(hv[j]); }
        axp[ks] = s;
    }
    // K projection -> Kbuf (+ f32 store iff OWN)
    #pragma unroll
    for (int ht = 0; ht < 8; ht++){
        short8 bw[4];
        #pragma unroll
        for (int ks = 0; ks < 4; ks++)
            bw[ks] = *(const short8*)(WT + (size_t)16384 + (size_t)(ht*16 + lq)*128 + ks*32 + quad*8);
        float4v c = {0.f,0.f,0.f,0.f};
        #pragma unroll
        for (int ks = 0; ks < 4; ks++)
            c = __builtin_amdgcn_mfma_f32_16x16x32_bf16(axp[ks], bw[ks], c, 0, 0, 0);
        #pragma unroll
        for (int r = 0; r < 4; r++){
            int keyl = lt*16 + quad*4 + r;
            if (OWN) kout[(size_t)(srcr0 + keyl)*128 + ht*16 + lq] = c[r];
            Kbuf[(ht>>1)*4096 + keyl*32 + (ht&1)*16 + lq] = f2bf(c[r]);
        }
    }
    // V projection (f32 store iff OWN) + V^T (swapped MFMA) -> VTbuf
    #pragma unroll
    for (int ht = 0; ht < 8; ht++){
        short8 bv[4];
        #pragma unroll
        for (int ks = 0; ks < 4; ks++)
            bv[ks] = *(const short8*)(WT + (size_t)2*16384 + (size_t)(ht*16 + lq)*128 + ks*32 + quad*8);
        if (OWN){
            float4v c = {0.f,0.f,0.f,0.f};
            #pragma unroll
            for (int ks = 0; ks < 4; ks++)
                c = __builtin_amdgcn_mfma_f32_16x16x32_bf16(axp[ks], bv[ks], c, 0, 0, 0);
            #pragma unroll
            for (int r = 0; r < 4; r++)
                vout[(size_t)(srcr0 + lt*16 + quad*4 + r)*128 + ht*16 + lq] = c[r];
        }
        float4v ct = {0.f,0.f,0.f,0.f};
        #pragma unroll
        for (int ks = 0; ks < 4; ks++)
            ct = __builtin_amdgcn_mfma_f32_16x16x32_bf16(bv[ks], axp[ks], ct, 0, 0, 0);
        int tl = lt*16 + lq;
        #pragma unroll
        for (int r = 0; r < 4; r++)
            VTbuf[(tl>>5)*4096 + (ht*16 + quad*4 + r)*32 + (tl&31)] = f2bf(ct[r]);
    }
}

template<bool DIAG>
__device__ __forceinline__ void attn_pass(const u16* Kbuf, const u16* VTbuf, u16* psw,
                                          const short8 (&qf)[4], float4v (&oacc)[8],
                                          float (&mrun)[4], float (&lrun)[4],
                                          int lt, int lq, int quad){
    #pragma unroll
    for (int kbL = 0; kbL < 2; kbL++){
        if (DIAG && kbL*4 > lt) continue;       // chunk above diagonal (wave-uniform)

        float4v s4[4];
        #pragma unroll
        for (int kt2 = 0; kt2 < 4; kt2++){
            int kt = kbL*4 + kt2;               // local key tile 0..7
            float4v c = {MASKV, MASKV, MASKV, MASKV};
            if (!DIAG || kt <= lt){
                c = (float4v){0.f,0.f,0.f,0.f};
                #pragma unroll
                for (int ks = 0; ks < 4; ks++){
                    short8 bb = *(const short8*)(Kbuf + ks*4096 + (kt*16 + lq)*32 + quad*8);
                    c = __builtin_amdgcn_mfma_f32_16x16x32_bf16(qf[ks], bb, c, 0, 0, 0);
                }
                #pragma unroll
                for (int r = 0; r < 4; r++)
                    c[r] = fminf(fmaxf(c[r], MASKV), 30000.0f);   // NaN/inf scrub
                if (DIAG && kt == lt){          // diagonal tile: mask key > row
                    #pragma unroll
                    for (int r = 0; r < 4; r++)
                        if (lq > quad*4 + r) c[r] = MASKV;
                }
            }
            s4[kt2] = c;
        }
        // online softmax update (quad's 16 lanes hold one row's 64 cols)
        #pragma unroll
        for (int r = 0; r < 4; r++){
            float mx = fmaxf(fmaxf(s4[0][r], s4[1][r]), fmaxf(s4[2][r], s4[3][r]));
            mx = fmaxf(mx, __shfl_xor(mx, 1));
            mx = fmaxf(mx, __shfl_xor(mx, 2));
            mx = fmaxf(mx, __shfl_xor(mx, 4));
            mx = fmaxf(mx, __shfl_xor(mx, 8));
            float mnew = fmaxf(mrun[r], mx);
            float alpha = __expf(mrun[r] - mnew);
            float rs = 0.f;
            #pragma unroll
            for (int kt2 = 0; kt2 < 4; kt2++){
                float pv = __expf(s4[kt2][r] - mnew);
                s4[kt2][r] = pv;
                rs += pv;
            }
            rs += __shfl_xor(rs, 1);
            rs += __shfl_xor(rs, 2);
            rs += __shfl_xor(rs, 4);
            rs += __shfl_xor(rs, 8);
            lrun[r] = lrun[r] * alpha + rs;
            mrun[r] = mnew;
            #pragma unroll
            for (int o = 0; o < 8; o++) oacc[o][r] *= alpha;
        }
        // P: C/D-layout -> per-wave LDS -> A-layout (same-wave ordering)
        #pragma unroll
        for (int kt2 = 0; kt2 < 4; kt2++)
            #pragma unroll
            for (int r = 0; r < 4; r++)
                psw[(quad*4 + r)*64 + kt2*16 + lq] = f2bf(s4[kt2][r]);
        short8 pa0 = *(const short8*)(psw + lq*64 + quad*8);
        short8 pa1 = *(const short8*)(psw + lq*64 + 32 + quad*8);
        // O += P V
        #pragma unroll
        for (int k2 = 0; k2 < 2; k2++){
            short8 pa = (k2 == 0) ? pa0 : pa1;
            #pragma unroll
            for (int o = 0; o < 8; o++){
                short8 vb = *(const short8*)(VTbuf + (kbL*2 + k2)*4096 + (o*16 + lq)*32 + quad*8);
                oacc[o] = __builtin_amdgcn_mfma_f32_16x16x32_bf16(pa, vb, oacc[o], 0, 0, 0);
            }
        }
    }
}

__global__ __launch_bounds__(512, 4) void fused_kernel(const float* __restrict__ x,
                                                       const u16* __restrict__ WT,
                                                       float* __restrict__ dout){
    __shared__ u16 Kbuf [4 * 128 * 32];   // 32 KB
    __shared__ u16 VTbuf[4 * 128 * 32];   // 32 KB
    __shared__ u16 ps   [8 * 1024];       // 16 KB

    int lb = blockIdx.x;
    int b = lb >> 1, hi = lb & 1;
    int r0 = hi << 7;                     // local row base of this half
    int tid = threadIdx.x;
    int w = tid >> 6, lane = tid & 63, lq = lane & 15, quad = lane >> 4;

    const int TILE8[8] = {0,7,3,4, 6,1,5,2};  // balances causal chunks per SIMD
    int lt = TILE8[w];                    // local 16-row tile within the half

    const float* xb   = x    + (size_t)b * 256 * 128;
    float*       oout = dout + (size_t)b * 256 * 128;
    float*       kout = dout + (size_t)BTH     + (size_t)b * 256 * 128;
    float*       vout = dout + (size_t)2 * BTH + (size_t)b * 256 * 128;

    // ---- Q projection for own rows -> per-wave scratch (Kbuf slice) -> A-frags
    short8 qf[4];
    {
        short8 axq[4];
        #pragma unroll
        for (int ks = 0; ks < 4; ks++){
            const float* px = xb + (size_t)(r0 + lt*16 + lq)*128 + ks*32 + quad*8;
            float4v lo = *(const float4v*)px;
            float4v hv = *(const float4v*)(px + 4);
            short8 s;
            #pragma unroll
            for (int j = 0; j < 4; j++){ s[j] = (short)f2bf(lo[j]); s[j+4] = (short)f2bf(hv[j]); }
            axq[ks] = s;
        }
        u16* qs = Kbuf + w * 2048;        // [16][128] u16 = 4096 B
        #pragma unroll
        for (int ht = 0; ht < 8; ht++){
            short8 bw[4];
            #pragma unroll
            for (int ks = 0; ks < 4; ks++)
                bw[ks] = *(const short8*)(WT + (size_t)(ht*16 + lq)*128 + ks*32 + quad*8);
            float4v c = {0.f,0.f,0.f,0.f};
            #pragma unroll
            for (int ks = 0; ks < 4; ks++)
                c = __builtin_amdgcn_mfma_f32_16x16x32_bf16(axq[ks], bw[ks], c, 0, 0, 0);
            #pragma unroll
            for (int r = 0; r < 4; r++)
                qs[(quad*4 + r)*128 + ht*16 + lq] = f2bf(c[r]);   // D: row=q-row, col=h
        }
        #pragma unroll
        for (int ks = 0; ks < 4; ks++)
            qf[ks] = *(const short8*)(qs + lq*128 + ks*32 + quad*8);  // A: row=lq
    }
    bar_lds();   // Q scratch dead; Kbuf may hold K

    // ---- online-softmax state
    float4v oacc[8];
    float mrun[4], lrun[4];
    #pragma unroll
    for (int o = 0; o < 8; o++) oacc[o] = (float4v){0.f,0.f,0.f,0.f};
    #pragma unroll
    for (int r = 0; r < 4; r++){ mrun[r] = MASKV; lrun[r] = 0.f; }
    u16* psw = ps + w * 1024;             // [16 rows][64 keys] bf16

    if (hi == 0){
        proj_pass<true >(xb, WT, kout, vout, Kbuf, VTbuf, 0, lt, lq, quad);
        bar_lds();
        attn_pass<true >(Kbuf, VTbuf, psw, qf, oacc, mrun, lrun, lt, lq, quad);
    } else {
        proj_pass<false>(xb, WT, kout, vout, Kbuf, VTbuf, 0, lt, lq, quad);
        bar_lds();
        attn_pass<false>(Kbuf, VTbuf, psw, qf, oacc, mrun, lrun, lt, lq, quad);
        bar_lds();   // all waves done reading Kbuf/VTbuf before overwrite
        proj_pass<true >(xb, WT, kout, vout, Kbuf, VTbuf, 128, lt, lq, quad);
        bar_lds();
        attn_pass<true >(Kbuf, VTbuf, psw, qf, oacc, mrun, lrun, lt, lq, quad);
    }

    // ---- epilogue: out = oacc / lrun
    #pragma unroll
    for (int r = 0; r < 4; r++){
        float inv = 1.0f / lrun[r];
        int row = r0 + lt*16 + quad*4 + r;
        #pragma unroll
        for (int o = 0; o < 8; o++)
            oout[(size_t)row*128 + o*16 + lq] = oacc[o][r] * inv;
    }
}

extern "C" void kernel_launch(void* const* d_in, const int* in_sizes, int n_in,
                              void* d_out, int out_size, void* d_ws, size_t ws_size,
                              hipStream_t stream){
    const float* x  = (const float*)d_in[0];
    const float* Wk = (const float*)d_in[1];
    const float* Wq = (const float*)d_in[2];
    const float* Wv = (const float*)d_in[3];
    float* out = (float*)d_out;
    u16* WT = (u16*)d_ws;                         // 96 KB (always available)

    wt_kernel   <<<192,  256, 0, stream>>>(Wq, Wk, Wv, WT);
    fused_kernel<<<1024, 512, 0, stream>>>(x, WT, out);
}

// Round 9
// 314.936 us; speedup vs baseline: 2.1329x; 1.4917x over previous
//
#include <hip/hip_runtime.h>

typedef unsigned short u16;
typedef __attribute__((ext_vector_type(8))) short short8;
typedef __attribute__((ext_vector_type(4))) float float4v;

#define BTH (512*256*128)   // elements per output tensor
#define MASKV (-30000.0f)

__device__ __forceinline__ u16 f2bf(float f){
    union{float f; unsigned i;} v; v.f = f;
    unsigned x = v.i;
    unsigned r = (x + 0x7FFFu + ((x >> 16) & 1u)) >> 16;  // RNE
    return (u16)r;
}

// LDS-only barrier: drains ds ops, NOT global stores (k/v/out stores have no
// in-kernel readers -> let them trickle to HBM under later compute phases).
__device__ __forceinline__ void bar_lds(){
    asm volatile("s_waitcnt lgkmcnt(0)" ::: "memory");
    __builtin_amdgcn_sched_barrier(0);
    __builtin_amdgcn_s_barrier();
}

// ---------------- Kernel 0: f32 weights -> bf16 WT[3][128 n][128 k]; fold C^-0.5 into Wq.
__global__ void wt_kernel(const float* __restrict__ Wq, const float* __restrict__ Wk,
                          const float* __restrict__ Wv, u16* __restrict__ WT){
    int idx = blockIdx.x * 256 + threadIdx.x;   // 0..49151
    int w   = idx >> 14;
    int rem = idx & 16383;
    int n = rem >> 7;
    int k = rem & 127;
    const float* src = (w == 0) ? Wq : (w == 1) ? Wk : Wv;
    float val = src[k * 128 + n];
    if (w == 0) val *= 0.08838834764831845f;    // 128^-0.5
    WT[idx] = f2bf(val);
}

// ============================================================================
// fused_kernel: one block = one batch; 512 blocks x 512 threads (8 waves).
// r5 base (best verified: 139us fused, zero spill) + 3 fixes:
//   1. rt pair {w, 15-w}: every wave exactly 5 causal chunks (r5: 4 vs 6).
//   2. full-row SINGLE-PASS softmax per rt (S in <=64 VGPR; regs are free at
//      1 block/CU + launch_bounds(512,1)) -- no online rescale, 5x fewer shfl.
//   3. bar_lds(): global k/v stores drain under attention, not at barriers.
//
// LDS (146 KiB, 1 block/CU):
//   Kbuf  [4 ks][256 key][32]  bf16 (64 KB)   K permuted
//   VTbuf [8 ck][128 h][32]    bf16 (64 KB)   V^T; pre-V: per-wave 8 KB
//                                             Q-scratch slice (stride 136)
//   ps    [8 wave][16][72]     bf16 (18 KB)   P transpose (padded stride)
// ============================================================================
__global__ __launch_bounds__(512, 1) void fused_kernel(const float* __restrict__ x,
                                                       const u16* __restrict__ WT,
                                                       float* __restrict__ dout){
    __shared__ u16 Kbuf [4 * 256 * 32];   // 64 KB
    __shared__ u16 VTbuf[8 * 128 * 32];   // 64 KB
    __shared__ u16 ps   [8 * 1152];       // 18 KB

    int b = blockIdx.x;
    int tid = threadIdx.x;
    int w = tid >> 6, lane = tid & 63, lq = lane & 15, quad = lane >> 4;

    const int rtg[2] = { w, 15 - w };     // chunk counts sum to 5 for every wave

    const float* xb   = x    + (size_t)b * 256 * 128;
    float*       oout = dout + (size_t)b * 256 * 128;
    float*       kout = dout + (size_t)BTH     + (size_t)b * 256 * 128;
    float*       vout = dout + (size_t)2 * BTH + (size_t)b * 256 * 128;

    // ---- x fragments for own 32 rows (f32 -> bf16), registers only
    short8 ax[2][4];
    #pragma unroll
    for (int rt = 0; rt < 2; rt++)
        #pragma unroll
        for (int ks = 0; ks < 4; ks++){
            const float* px = xb + (size_t)(rtg[rt]*16 + lq)*128 + ks*32 + quad*8;
            float4v lo = *(const float4v*)px;
            float4v hv = *(const float4v*)(px + 4);
            short8 s;
            #pragma unroll
            for (int j = 0; j < 4; j++){ s[j] = (short)f2bf(lo[j]); s[j+4] = (short)f2bf(hv[j]); }
            ax[rt][ks] = s;
        }

    // ---- Q projection -> per-wave scratch (VTbuf slice, stride 136) -> A-frags
    u16* qs = VTbuf + w * 4096;           // [16][136] u16 = 4352 B < 8192 B slice
    short8 qf[2][4];
    #pragma unroll
    for (int rt = 0; rt < 2; rt++){
        #pragma unroll
        for (int ht = 0; ht < 8; ht++){
            short8 bw[4];
            #pragma unroll
            for (int ks = 0; ks < 4; ks++)
                bw[ks] = *(const short8*)(WT + (size_t)(ht*16 + lq)*128 + ks*32 + quad*8);
            float4v c = {0.f,0.f,0.f,0.f};
            #pragma unroll
            for (int ks = 0; ks < 4; ks++)
                c = __builtin_amdgcn_mfma_f32_16x16x32_bf16(ax[rt][ks], bw[ks], c, 0, 0, 0);
            #pragma unroll
            for (int r = 0; r < 4; r++)
                qs[(quad*4 + r)*136 + ht*16 + lq] = f2bf(c[r]);   // D: row=q-row, col=h
        }
        #pragma unroll
        for (int ks = 0; ks < 4; ks++)
            qf[rt][ks] = *(const short8*)(qs + lq*136 + ks*32 + quad*8);  // A: row=lq
    }
    bar_lds();   // Q scratch dead; VTbuf may hold V^T

    // ---- K projection -> Kbuf (permuted) + f32 k out.  ht-outer: Wk frags once.
    #pragma unroll
    for (int ht = 0; ht < 8; ht++){
        short8 bw[4];
        #pragma unroll
        for (int ks = 0; ks < 4; ks++)
            bw[ks] = *(const short8*)(WT + (size_t)16384 + (size_t)(ht*16 + lq)*128 + ks*32 + quad*8);
        #pragma unroll
        for (int rt = 0; rt < 2; rt++){
            float4v c = {0.f,0.f,0.f,0.f};
            #pragma unroll
            for (int ks = 0; ks < 4; ks++)
                c = __builtin_amdgcn_mfma_f32_16x16x32_bf16(ax[rt][ks], bw[ks], c, 0, 0, 0);
            #pragma unroll
            for (int r = 0; r < 4; r++){
                int key = rtg[rt]*16 + quad*4 + r;
                kout[(size_t)key*128 + ht*16 + lq] = c[r];
                Kbuf[(ht>>1)*8192 + key*32 + (ht&1)*16 + lq] = f2bf(c[r]);
            }
        }
    }

    // ---- V projection (f32 out) + V^T (swapped MFMA) -> VTbuf.  Wv frags once.
    #pragma unroll
    for (int ht = 0; ht < 8; ht++){
        short8 bv[4];
        #pragma unroll
        for (int ks = 0; ks < 4; ks++)
            bv[ks] = *(const short8*)(WT + (size_t)2*16384 + (size_t)(ht*16 + lq)*128 + ks*32 + quad*8);
        #pragma unroll
        for (int rt = 0; rt < 2; rt++){
            float4v c = {0.f,0.f,0.f,0.f};
            #pragma unroll
            for (int ks = 0; ks < 4; ks++)
                c = __builtin_amdgcn_mfma_f32_16x16x32_bf16(ax[rt][ks], bv[ks], c, 0, 0, 0);
            #pragma unroll
            for (int r = 0; r < 4; r++)
                vout[(size_t)(rtg[rt]*16 + quad*4 + r)*128 + ht*16 + lq] = c[r];
            float4v ct = {0.f,0.f,0.f,0.f};
            #pragma unroll
            for (int ks = 0; ks < 4; ks++)
                ct = __builtin_amdgcn_mfma_f32_16x16x32_bf16(bv[ks], ax[rt][ks], ct, 0, 0, 0);
            int t = rtg[rt]*16 + lq;
            #pragma unroll
            for (int r = 0; r < 4; r++)
                VTbuf[(t>>5)*4096 + (ht*16 + quad*4 + r)*32 + (t&31)] = f2bf(ct[r]);
        }
    }
    bar_lds();   // K and V^T images complete

    // ---- attention, one rt at a time: full-row S in regs, single-pass softmax
    u16* psw = ps + w * 1152;             // [16 rows][72] bf16
    #pragma unroll
    for (int rt = 0; rt < 2; rt++){
        int rg = rtg[rt];
        int nch = (rg >> 2) + 1;          // 1..4 chunks of 64 keys (wave-uniform)

        // S = Q K^T for all chunks (<=16 key-tiles), back-to-back MFMAs
        float4v s[4][4];                  // [kb][kt2]
        #pragma unroll
        for (int kb = 0; kb < 4; kb++){
            if (kb >= nch) continue;
            #pragma unroll
            for (int kt2 = 0; kt2 < 4; kt2++){
                int kt = kb*4 + kt2;
                float4v c = {MASKV, MASKV, MASKV, MASKV};
                if (kt <= rg){
                    c = (float4v){0.f,0.f,0.f,0.f};
                    #pragma unroll
                    for (int ks = 0; ks < 4; ks++){
                        short8 bb = *(const short8*)(Kbuf + ks*8192 + (kt*16 + lq)*32 + quad*8);
                        c = __builtin_amdgcn_mfma_f32_16x16x32_bf16(qf[rt][ks], bb, c, 0, 0, 0);
                    }
                    #pragma unroll
                    for (int r = 0; r < 4; r++)
                        c[r] = fminf(fmaxf(c[r], MASKV), 30000.0f);   // NaN/inf scrub
                    if (kt == rg){        // diagonal tile: mask key > row
                        #pragma unroll
                        for (int r = 0; r < 4; r++)
                            if (lq > quad*4 + r) c[r] = MASKV;
                    }
                }
                s[kb][kt2] = c;
            }
        }
        // single-pass softmax: in-lane reduce over all chunks, then 4 shfl
        float lsum[4];
        #pragma unroll
        for (int r = 0; r < 4; r++){
            float mx = MASKV;
            #pragma unroll
            for (int kb = 0; kb < 4; kb++){
                if (kb >= nch) continue;
                #pragma unroll
                for (int kt2 = 0; kt2 < 4; kt2++)
                    mx = fmaxf(mx, s[kb][kt2][r]);
            }
            mx = fmaxf(mx, __shfl_xor(mx, 1));
            mx = fmaxf(mx, __shfl_xor(mx, 2));
            mx = fmaxf(mx, __shfl_xor(mx, 4));
            mx = fmaxf(mx, __shfl_xor(mx, 8));
            float rs = 0.f;
            #pragma unroll
            for (int kb = 0; kb < 4; kb++){
                if (kb >= nch) continue;
                #pragma unroll
                for (int kt2 = 0; kt2 < 4; kt2++){
                    float pv = __expf(s[kb][kt2][r] - mx);
                    s[kb][kt2][r] = pv;   // S becomes P in place
                    rs += pv;
                }
            }
            rs += __shfl_xor(rs, 1);
            rs += __shfl_xor(rs, 2);
            rs += __shfl_xor(rs, 4);
            rs += __shfl_xor(rs, 8);
            lsum[r] = rs;
        }
        // O = P V over the chunks (P -> per-wave LDS -> A-frags; same-wave order)
        float4v oacc[8];
        #pragma unroll
        for (int o = 0; o < 8; o++) oacc[o] = (float4v){0.f,0.f,0.f,0.f};
        #pragma unroll
        for (int kb = 0; kb < 4; kb++){
            if (kb >= nch) continue;
            #pragma unroll
            for (int kt2 = 0; kt2 < 4; kt2++)
                #pragma unroll
                for (int r = 0; r < 4; r++)
                    psw[(quad*4 + r)*72 + kt2*16 + lq] = f2bf(s[kb][kt2][r]);
            short8 pa0 = *(const short8*)(psw + lq*72 + quad*8);
            short8 pa1 = *(const short8*)(psw + lq*72 + 32 + quad*8);
            #pragma unroll
            for (int k2 = 0; k2 < 2; k2++){
                short8 pa = (k2 == 0) ? pa0 : pa1;
                #pragma unroll
                for (int o = 0; o < 8; o++){
                    short8 vb = *(const short8*)(VTbuf + (kb*2 + k2)*4096 + (o*16 + lq)*32 + quad*8);
                    oacc[o] = __builtin_amdgcn_mfma_f32_16x16x32_bf16(pa, vb, oacc[o], 0, 0, 0);
                }
            }
        }
        // epilogue for this rt
        #pragma unroll
        for (int r = 0; r < 4; r++){
            float inv = 1.0f / lsum[r];
            int row = rg*16 + quad*4 + r;
            #pragma unroll
            for (int o = 0; o < 8; o++)
                oout[(size_t)row*128 + o*16 + lq] = oacc[o][r] * inv;
        }
    }
}

extern "C" void kernel_launch(void* const* d_in, const int* in_sizes, int n_in,
                              void* d_out, int out_size, void* d_ws, size_t ws_size,
                              hipStream_t stream){
    const float* x  = (const float*)d_in[0];
    const float* Wk = (const float*)d_in[1];
    const float* Wq = (const float*)d_in[2];
    const float* Wv = (const float*)d_in[3];
    float* out = (float*)d_out;
    u16* WT = (u16*)d_ws;                         // 96 KB (always available)

    wt_kernel   <<<192, 256, 0, stream>>>(Wq, Wk, Wv, WT);
    fused_kernel<<<512, 512, 0, stream>>>(x, WT, out);
}